// Round 2
// baseline (127.329 us; speedup 1.0000x reference)
//
#include <hip/hip_runtime.h>
#include <hip/hip_bf16.h>

// NT-Xent (SimCLR) loss, B=4096, D=256, N=8192, T=0.5.
// loss = [ sum_i log(sum_{j!=i} exp(sim_ij * 2)) - 4 * sum_{i<B} pos_i ] / N
// sim is symmetric: compute only upper-triangle 256x256 tiles (528 of 1024).
// Each tile emits BOTH row-sums (reduce over MFMA C regs, free) and col-sums
// (DPP lane-reduce -> LDS colacc -> one atomicAdd per column).
// Finalize is fused into the sim kernel via a last-block-done counter:
// 2 dispatches total (normalize, simexp+finalize).

constexpr int BB = 4096;                 // batch
constexpr int NN = 8192;                 // 2*batch
constexpr int DD = 256;                  // feature dim
constexpr int TILE = 256;                // square tile edge
constexpr int NT = NN / TILE;            // 32 tile rows/cols
constexpr int NBLK = NT * (NT + 1) / 2;  // 528 upper-tri blocks (528 = 8*66)
constexpr int CSTEPS = TILE / 32;        // 8 c-steps per block

typedef _Float16 half4v __attribute__((ext_vector_type(4)));
typedef _Float16 half8v __attribute__((ext_vector_type(8)));
typedef float floatx16 __attribute__((ext_vector_type(16)));

// ---------------- Kernel 1: normalize rows -> f16, pos partials, zero accums -
__global__ __launch_bounds__(256) void nt_normalize(
    const float* __restrict__ zi, const float* __restrict__ zj,
    _Float16* __restrict__ Z, float* __restrict__ posPartial,
    float* __restrict__ rowsum, int* __restrict__ doneCnt)
{
    const int lane = threadIdx.x & 63;
    const int wave = threadIdx.x >> 6;
    const int i = blockIdx.x * 4 + wave;   // pair index, < BB

    // Zero rowsum (8192 floats) with the first 32 blocks; simexp runs after
    // this dispatch completes (stream order), so no race.
    if (blockIdx.x < 32) rowsum[blockIdx.x * 256 + threadIdx.x] = 0.f;
    if (blockIdx.x == 32 && threadIdx.x == 0) doneCnt[0] = 0;

    const float4 a = ((const float4*)(zi + (size_t)i * DD))[lane];
    const float4 b = ((const float4*)(zj + (size_t)i * DD))[lane];

    float ssi = a.x*a.x + a.y*a.y + a.z*a.z + a.w*a.w;
    float ssj = b.x*b.x + b.y*b.y + b.z*b.z + b.w*b.w;
    float dd  = a.x*b.x + a.y*b.y + a.z*b.z + a.w*b.w;
#pragma unroll
    for (int off = 32; off > 0; off >>= 1) {
        ssi += __shfl_xor(ssi, off);
        ssj += __shfl_xor(ssj, off);
        dd  += __shfl_xor(dd,  off);
    }
    const float invi = rsqrtf(ssi);
    const float invj = rsqrtf(ssj);

    half4v ha, hb;
    ha.x = (_Float16)(a.x * invi); ha.y = (_Float16)(a.y * invi);
    ha.z = (_Float16)(a.z * invi); ha.w = (_Float16)(a.w * invi);
    hb.x = (_Float16)(b.x * invj); hb.y = (_Float16)(b.y * invj);
    hb.z = (_Float16)(b.z * invj); hb.w = (_Float16)(b.w * invj);

    ((half4v*)(Z + (size_t)i * DD))[lane]        = ha;
    ((half4v*)(Z + (size_t)(BB + i) * DD))[lane] = hb;

    __shared__ float ps[4];
    if (lane == 0) ps[wave] = dd * invi * invj;
    __syncthreads();
    if (threadIdx.x == 0)
        posPartial[blockIdx.x] = ps[0] + ps[1] + ps[2] + ps[3];
}

// DPP half-wave reduce: after this, lane31 = sum(lanes 0..31),
// lane63 = sum(lanes 32..63). rocPRIM pattern: row_shr 1/2/4/8 prefix,
// then row_bcast:15 into rows 1 and 3 (row_mask 0xa). VALU pipe only.
__device__ __forceinline__ float half_sums(float x) {
    int t;
    t = __builtin_amdgcn_update_dpp(0, __builtin_bit_cast(int, x), 0x111, 0xf, 0xf, false);
    x += __builtin_bit_cast(float, t);
    t = __builtin_amdgcn_update_dpp(0, __builtin_bit_cast(int, x), 0x112, 0xf, 0xf, false);
    x += __builtin_bit_cast(float, t);
    t = __builtin_amdgcn_update_dpp(0, __builtin_bit_cast(int, x), 0x114, 0xf, 0xf, false);
    x += __builtin_bit_cast(float, t);
    t = __builtin_amdgcn_update_dpp(0, __builtin_bit_cast(int, x), 0x118, 0xf, 0xf, false);
    x += __builtin_bit_cast(float, t);
    t = __builtin_amdgcn_update_dpp(0, __builtin_bit_cast(int, x), 0x142, 0xa, 0xf, false);
    x += __builtin_bit_cast(float, t);
    return x;
}

// ---------------- Kernel 2: upper-tri sim-GEMM + exp + row/col sums + finalize
// Grid: 528 blocks, 256 threads (4 waves). Block (rt,ct), rt<=ct, computes the
// 256x256 tile; wave owns 64 r-rows (B-operand in regs, whole K=256); c-rows
// staged 32 at a time into double-buffered swizzled LDS (1 barrier/step).
// Off-diag tiles: row-sums (reg reduce) AND col-sums (DPP reduce -> colacc).
// Diag tiles: row-sums only, diagonal element masked.
// The last block to finish computes the loss from rowsum (atomic coherent
// loads) and posPartial (written by the previous dispatch).
__global__ __launch_bounds__(256, 2) void nt_simexp(
    const _Float16* __restrict__ Z, float* __restrict__ rowsum,
    const float* __restrict__ posPartial, int* __restrict__ doneCnt,
    float* __restrict__ out)
{
    __shared__ _Float16 lds[2][32 * DD];   // 2 x 16 KB, 16B-granule swizzled
    __shared__ float colacc[TILE];         // per-block column accumulators
    __shared__ int sIsLast;

    // Bijective XCD swizzle (528 % 8 == 0): contiguous 66-block chunk per XCD.
    int bid = (blockIdx.x & 7) * (NBLK / 8) + (blockIdx.x >> 3);

    // Triangular map bid -> (rt, ct), rt <= ct.
    int rt = 0, rem = bid;
    while (rem >= NT - rt) { rem -= NT - rt; ++rt; }
    const int ct = rt + rem;
    const bool diag = (rt == ct);

    const int tid = threadIdx.x;
    const int wave = tid >> 6;
    const int lane = tid & 63;
    const int lm = lane & 31;           // MFMA row/col index within 32
    const int lh = lane >> 5;           // half select

    const int rbase = rt * TILE + wave * 64;  // this wave's 64 r-rows
    const int cbase0 = ct * TILE;

    colacc[tid] = 0.f;                  // visible after first __syncthreads

    // B fragments for both 32-row sets, all 16 k-steps, held in registers.
    half8v bfrag[2][16];
#pragma unroll
    for (int b = 0; b < 2; ++b) {
        const _Float16* rowp = Z + (size_t)(rbase + b * 32 + lm) * DD + lh * 8;
#pragma unroll
        for (int s = 0; s < 16; ++s)
            bfrag[b][s] = *(const half8v*)(rowp + s * 16);
    }

    // Staging granule coords for this thread (4 granules of 16B per tile).
    const int g_c0 = tid >> 5;          // c row for it=0
    const int g_kc = tid & 31;

    half8v pre[4];
    auto loadTile = [&](int crow0) {
#pragma unroll
        for (int it = 0; it < 4; ++it) {
            const int c = g_c0 + it * 8;
            pre[it] = *(const half8v*)(Z + (size_t)(crow0 + c) * DD + g_kc * 8);
        }
    };
    auto storeTile = [&](int bi) {
#pragma unroll
        for (int it = 0; it < 4; ++it) {
            const int c = g_c0 + it * 8;
            *(half8v*)(&lds[bi][c * DD + (g_kc ^ (c & 7)) * 8]) = pre[it];
        }
    };

    float ea0 = 0.f, ea1 = 0.f;
    const float KEXP = 2.0f * 1.44269504088896340736f;  // (1/T) * log2(e)

    loadTile(cbase0);
    storeTile(0);

    for (int cs = 0; cs < CSTEPS; ++cs) {
        __syncthreads();                 // buf[cs&1] ready; prev reads done
        if (cs + 1 < CSTEPS) loadTile(cbase0 + (cs + 1) * 32);

        const _Float16* buf = lds[cs & 1];
        floatx16 c0, c1;
#pragma unroll
        for (int r = 0; r < 16; ++r) { c0[r] = 0.f; c1[r] = 0.f; }

#pragma unroll
        for (int s = 0; s < 16; ++s) {
            const int phys = (2 * s + lh) ^ (lm & 7);
            half8v af = *(const half8v*)(&buf[lm * DD + phys * 8]);
            c0 = __builtin_amdgcn_mfma_f32_32x32x16_f16(af, bfrag[0][s], c0, 0, 0, 0);
            c1 = __builtin_amdgcn_mfma_f32_32x32x16_f16(af, bfrag[1][s], c1, 0, 0, 0);
        }

        if (!diag) {
            // exp, row accumulate (per-lane over regs) + column reduce (DPP).
#pragma unroll
            for (int r = 0; r < 16; ++r) {
                float e0 = __builtin_amdgcn_exp2f(c0[r] * KEXP);
                float e1 = __builtin_amdgcn_exp2f(c1[r] * KEXP);
                ea0 += e0; ea1 += e1;
                float s2 = half_sums(e0 + e1);   // lanes 31/63 hold half-sums
                if (lm == 31) {                  // lanes 31 and 63
                    const int cidx = cs * 32 + (r & 3) + 8 * (r >> 2) + 4 * lh;
                    atomicAdd(&colacc[cidx], s2);    // ds_add_f32
                }
            }
        } else {
            const bool m0 = (cs == 2 * wave);
            const bool m1 = (cs == 2 * wave + 1);
#pragma unroll
            for (int r = 0; r < 16; ++r) {
                const int mrow = (r & 3) + 8 * (r >> 2) + 4 * lh;
                float e0 = __builtin_amdgcn_exp2f(c0[r] * KEXP);
                float e1 = __builtin_amdgcn_exp2f(c1[r] * KEXP);
                if (m0 && (mrow == lm)) e0 = 0.f;
                if (m1 && (mrow == lm)) e1 = 0.f;
                ea0 += e0; ea1 += e1;
            }
        }

        if (cs + 1 < CSTEPS) storeTile((cs + 1) & 1);
    }

    // Row sums: combine the two lane-halves (different mrow column sets).
    ea0 += __shfl_xor(ea0, 32);
    ea1 += __shfl_xor(ea1, 32);
    if (lane < 32) {
        atomicAdd(&rowsum[rbase + lm], ea0);
        atomicAdd(&rowsum[rbase + 32 + lm], ea1);
    }

    // Column sums (mirror contribution) — off-diagonal tiles only.
    if (!diag) {
        __syncthreads();
        atomicAdd(&rowsum[cbase0 + tid], colacc[tid]);
    }

    // ---------------- fused finalize: last block computes the loss ----------
    __threadfence();                     // release rowsum atomics
    if (tid == 0)
        sIsLast = (atomicAdd(doneCnt, 1) == NBLK - 1);
    __syncthreads();
    if (!sIsLast) return;

    // Coherent reads of rowsum via atomic RMW (device scope, cross-XCD safe).
    float acc = 0.f;
#pragma unroll
    for (int it = 0; it < NN / 256; ++it)
        acc += __builtin_amdgcn_logf(atomicAdd(&rowsum[tid + it * 256], 0.f)); // log2
    float pacc = 0.f;
#pragma unroll
    for (int it = 0; it < 4; ++it)
        pacc += posPartial[tid + it * 256];   // written by prev dispatch

#pragma unroll
    for (int off = 32; off > 0; off >>= 1) {
        acc  += __shfl_xor(acc,  off);
        pacc += __shfl_xor(pacc, off);
    }
    __shared__ float sa[4], sp[4];
    if ((tid & 63) == 0) { sa[wave] = acc; sp[wave] = pacc; }
    __syncthreads();
    if (tid == 0) {
        const float lntot = (sa[0] + sa[1] + sa[2] + sa[3]) * 0.6931471805599453f;
        const float ptot  = sp[0] + sp[1] + sp[2] + sp[3];
        out[0] = (lntot - 4.0f * ptot) * (1.0f / (float)NN);
    }
}

// ---------------- Launch ------------------------------------------------------
extern "C" void kernel_launch(void* const* d_in, const int* in_sizes, int n_in,
                              void* d_out, int out_size, void* d_ws, size_t ws_size,
                              hipStream_t stream) {
    const float* zi = (const float*)d_in[0];
    const float* zj = (const float*)d_in[1];
    float* out = (float*)d_out;

    _Float16* Z = (_Float16*)d_ws;                                  // 4 MB
    float* rowsum = (float*)((char*)d_ws + (size_t)NN * DD * 2);    // 32 KB
    float* posPartial = rowsum + NN;                                // 4 KB
    int* doneCnt = (int*)(posPartial + 1024);                       // 4 B

    nt_normalize<<<BB / 4, 256, 0, stream>>>(zi, zj, Z, posPartial, rowsum, doneCnt);
    nt_simexp<<<NBLK, 256, 0, stream>>>((const _Float16*)Z, rowsum, posPartial,
                                        doneCnt, out);
}

// Round 3
// 91.302 us; speedup vs baseline: 1.3946x; 1.3946x over previous
//
#include <hip/hip_runtime.h>
#include <hip/hip_bf16.h>

// NT-Xent (SimCLR) loss, B=4096, D=256, N=8192, T=0.5.
// loss = [ sum_i log(sum_{j!=i} exp(sim_ij * 2)) - 4 * sum_{i<B} pos_i ] / N
// sim symmetric: upper-triangle 128x128 tiles only (2080 of 4096). Each tile
// emits row-sums for BOTH its row-range (DPP lane reduce -> colacc) and its
// col-range (per-lane reg reduce). 3 dispatches; no device fences.

constexpr int BB = 4096;                 // batch
constexpr int NN = 8192;                 // 2*batch
constexpr int DD = 256;                  // feature dim
constexpr int TS = 128;                  // tile edge
constexpr int NT = NN / TS;              // 64 tile rows/cols
constexpr int NBLK = NT * (NT + 1) / 2;  // 2080 = 8*260
constexpr int KCH = 64;                  // k-chunk (halfs)
constexpr int NCH = DD / KCH;            // 4 chunks

typedef _Float16 half4v __attribute__((ext_vector_type(4)));
typedef _Float16 half8v __attribute__((ext_vector_type(8)));
typedef float floatx16 __attribute__((ext_vector_type(16)));

// ---------------- Kernel 1: normalize rows -> f16, pos partials, zero rowsum -
__global__ __launch_bounds__(256) void nt_normalize(
    const float* __restrict__ zi, const float* __restrict__ zj,
    _Float16* __restrict__ Z, float* __restrict__ posPartial,
    float* __restrict__ rowsum)
{
    const int lane = threadIdx.x & 63;
    const int wave = threadIdx.x >> 6;
    const int i = blockIdx.x * 4 + wave;   // pair index, < BB

    if (blockIdx.x < 32) rowsum[blockIdx.x * 256 + threadIdx.x] = 0.f;

    const float4 a = ((const float4*)(zi + (size_t)i * DD))[lane];
    const float4 b = ((const float4*)(zj + (size_t)i * DD))[lane];

    float ssi = a.x*a.x + a.y*a.y + a.z*a.z + a.w*a.w;
    float ssj = b.x*b.x + b.y*b.y + b.z*b.z + b.w*b.w;
    float dd  = a.x*b.x + a.y*b.y + a.z*b.z + a.w*b.w;
#pragma unroll
    for (int off = 32; off > 0; off >>= 1) {
        ssi += __shfl_xor(ssi, off);
        ssj += __shfl_xor(ssj, off);
        dd  += __shfl_xor(dd,  off);
    }
    const float invi = rsqrtf(ssi);
    const float invj = rsqrtf(ssj);

    half4v ha, hb;
    ha.x = (_Float16)(a.x * invi); ha.y = (_Float16)(a.y * invi);
    ha.z = (_Float16)(a.z * invi); ha.w = (_Float16)(a.w * invi);
    hb.x = (_Float16)(b.x * invj); hb.y = (_Float16)(b.y * invj);
    hb.z = (_Float16)(b.z * invj); hb.w = (_Float16)(b.w * invj);

    ((half4v*)(Z + (size_t)i * DD))[lane]        = ha;
    ((half4v*)(Z + (size_t)(BB + i) * DD))[lane] = hb;

    __shared__ float ps[4];
    if (lane == 0) ps[wave] = dd * invi * invj;
    __syncthreads();
    if (threadIdx.x == 0)
        posPartial[blockIdx.x] = ps[0] + ps[1] + ps[2] + ps[3];
}

// DPP half-wave reduce: lane31 = sum(lanes 0..31), lane63 = sum(lanes 32..63).
__device__ __forceinline__ float half_sums(float x) {
    int t;
    t = __builtin_amdgcn_update_dpp(0, __builtin_bit_cast(int, x), 0x111, 0xf, 0xf, false);
    x += __builtin_bit_cast(float, t);
    t = __builtin_amdgcn_update_dpp(0, __builtin_bit_cast(int, x), 0x112, 0xf, 0xf, false);
    x += __builtin_bit_cast(float, t);
    t = __builtin_amdgcn_update_dpp(0, __builtin_bit_cast(int, x), 0x114, 0xf, 0xf, false);
    x += __builtin_bit_cast(float, t);
    t = __builtin_amdgcn_update_dpp(0, __builtin_bit_cast(int, x), 0x118, 0xf, 0xf, false);
    x += __builtin_bit_cast(float, t);
    t = __builtin_amdgcn_update_dpp(0, __builtin_bit_cast(int, x), 0x142, 0xa, 0xf, false);
    x += __builtin_bit_cast(float, t);
    return x;
}

// ---------------- Kernel 2: upper-tri sim-GEMM + exp + row/col sums ----------
// Grid: 2080 blocks x 256 thr (4 waves). Block (rt,ct): 128x128 tile.
// Wave (wr,wc) = (wave>>1, wave&1) computes 64x64 quadrant: acc[2][2] 32x32
// MFMA tiles (64 VGPR). K chunked by 64: A rows (rt side) and B rows (ct side)
// staged in LDS via global_load_lds (16B, pre-swizzled source, linear dest).
// 4 blocks/CU (launch_bounds(256,4), LDS 33 KB) for latency hiding.
__global__ __launch_bounds__(256, 4) void nt_simexp(
    const _Float16* __restrict__ Z, float* __restrict__ rowsum)
{
    __shared__ _Float16 As[TS * KCH];   // 16 KB
    __shared__ _Float16 Bs[TS * KCH];   // 16 KB
    __shared__ float colacc[TS];        // 512 B

    // Bijective XCD swizzle (2080 % 8 == 0).
    const int bid = (blockIdx.x & 7) * (NBLK / 8) + (blockIdx.x >> 3);

    // Triangular map bid -> (rt, ct), rt <= ct.
    int rt = 0, rem = bid;
    while (rem >= NT - rt) { rem -= NT - rt; ++rt; }
    const int ct = rt + rem;
    const bool diag = (rt == ct);

    const int tid = threadIdx.x;
    const int wave = tid >> 6;
    const int lane = tid & 63;
    const int lm = lane & 31;
    const int lh = lane >> 5;
    const int wr = wave >> 1;           // row half (A side)
    const int wc = wave & 1;            // col half (B side)

    const int rbase = rt * TS;          // A-side rows (output rows)
    const int cbase = ct * TS;          // B-side rows (output cols)

    if (tid < TS) colacc[tid] = 0.f;

    // Staging geometry: call c covers LDS granules 64c..64c+63 = rows 8c..8c+7.
    // Stored content is column-granule-swizzled: LDS[row][g] = SRC[row][g ^ (row&7)]
    // achieved by pre-swizzling the per-lane GLOBAL source (linear LDS dest).
    const int st_row = (lane >> 3);               // 0..7 within call
    const int st_sg  = (lane & 7) ^ (lane >> 3);  // source granule
    auto stage = [&](const _Float16* srcBase, _Float16* ldsBase, int ch) {
#pragma unroll
        for (int j = 0; j < 4; ++j) {
            const int c = wave * 4 + j;           // 0..15
            const _Float16* g = srcBase + (size_t)(8 * c + st_row) * DD
                                        + ch * KCH + st_sg * 8;
            __builtin_amdgcn_global_load_lds(
                (const __attribute__((address_space(1))) unsigned int*)g,
                (__attribute__((address_space(3))) unsigned int*)(ldsBase + c * 512),
                16, 0, 0);
        }
    };

    floatx16 a00, a01, a10, a11;
#pragma unroll
    for (int r = 0; r < 16; ++r) { a00[r] = 0.f; a01[r] = 0.f; a10[r] = 0.f; a11[r] = 0.f; }

    const _Float16* Ar = Z + (size_t)rbase * DD;
    const _Float16* Br = Z + (size_t)cbase * DD;

    for (int ch = 0; ch < NCH; ++ch) {
        __syncthreads();                       // prev chunk reads complete
        stage(Ar, As, ch);
        stage(Br, Bs, ch);
        asm volatile("s_waitcnt vmcnt(0)" ::: "memory");
        __syncthreads();                       // chunk staged

#pragma unroll
        for (int s = 0; s < 4; ++s) {
            const int pg = 2 * s + lh;         // logical granule
            const int ph = (pg ^ (lm & 7)) * 8;
            half8v fa0 = *(const half8v*)&As[(wr * 64 + lm) * KCH + ph];
            half8v fa1 = *(const half8v*)&As[(wr * 64 + 32 + lm) * KCH + ph];
            half8v fb0 = *(const half8v*)&Bs[(wc * 64 + lm) * KCH + ph];
            half8v fb1 = *(const half8v*)&Bs[(wc * 64 + 32 + lm) * KCH + ph];
            a00 = __builtin_amdgcn_mfma_f32_32x32x16_f16(fa0, fb0, a00, 0, 0, 0);
            a01 = __builtin_amdgcn_mfma_f32_32x32x16_f16(fa0, fb1, a01, 0, 0, 0);
            a10 = __builtin_amdgcn_mfma_f32_32x32x16_f16(fa1, fb0, a10, 0, 0, 0);
            a11 = __builtin_amdgcn_mfma_f32_32x32x16_f16(fa1, fb1, a11, 0, 0, 0);
        }
    }

    // Epilogue: e = exp2(sim * 2*log2e). Per-lane reg sums -> col-range rows
    // (B side, index lm); DPP across lm -> row-range rows (A side, index mrow).
    const float KEXP = 2.0f * 1.44269504088896340736f;
    float eb0 = 0.f, eb1 = 0.f;
#pragma unroll
    for (int tr = 0; tr < 2; ++tr) {
#pragma unroll
        for (int r = 0; r < 16; ++r) {
            const int mrow = (r & 3) + 8 * (r >> 2) + 4 * lh;
            float e0 = __builtin_amdgcn_exp2f((tr ? a10[r] : a00[r]) * KEXP);
            float e1 = __builtin_amdgcn_exp2f((tr ? a11[r] : a01[r]) * KEXP);
            if (diag && (wr == wc) && (mrow == lm)) {
                if (tr == 0) e0 = 0.f; else e1 = 0.f;   // tc == tr on diagonal
            }
            // (diagonal element lies where wr==wc, tr==tc, mrow==lm)
            if (diag && (wr == wc) && (mrow == lm) && (tr == 1)) e0 = e0; // no-op
            eb0 += e0; eb1 += e1;
            if (!diag) {
                float s2 = half_sums(e0 + e1);
                if (lm == 31)
                    atomicAdd(&colacc[wr * 64 + tr * 32 + mrow], s2);
            }
        }
    }

    // Wait: diagonal mask above is wrong for (tr,tc) pairing. Redo exactly:
    // masked element: global row == global col ->
    //   wr==wc && tr==tc && mrow==lm. For tr loop, e0 is tc=0, e1 is tc=1.
    // The code above already zeroes (tr==0 -> e0) and (tr==1 -> e1): correct.

    eb0 += __shfl_xor(eb0, 32);
    eb1 += __shfl_xor(eb1, 32);
    if (lane < 32) {
        atomicAdd(&rowsum[cbase + wc * 64 + lm], eb0);
        atomicAdd(&rowsum[cbase + wc * 64 + 32 + lm], eb1);
    }
    if (!diag) {
        __syncthreads();
        if (tid < TS) atomicAdd(&rowsum[rbase + tid], colacc[tid]);
    }
}

// ---------------- Kernel 3: finalize ----------------------------------------
__global__ __launch_bounds__(256) void nt_finalize(
    const float* __restrict__ rowsum, const float* __restrict__ posPartial,
    float* __restrict__ out)
{
    const int tid = threadIdx.x;
    float acc = 0.f;
#pragma unroll
    for (int it = 0; it < NN / 256; ++it)
        acc += __builtin_amdgcn_logf(rowsum[tid + it * 256]);   // log2
    float pacc = 0.f;
#pragma unroll
    for (int it = 0; it < 4; ++it)
        pacc += posPartial[tid + it * 256];

#pragma unroll
    for (int off = 32; off > 0; off >>= 1) {
        acc  += __shfl_xor(acc,  off);
        pacc += __shfl_xor(pacc, off);
    }
    __shared__ float sa[4], sp[4];
    const int wave = tid >> 6;
    if ((tid & 63) == 0) { sa[wave] = acc; sp[wave] = pacc; }
    __syncthreads();
    if (tid == 0) {
        const float lntot = (sa[0] + sa[1] + sa[2] + sa[3]) * 0.6931471805599453f;
        const float ptot  = sp[0] + sp[1] + sp[2] + sp[3];
        out[0] = (lntot - 4.0f * ptot) * (1.0f / (float)NN);
    }
}

// ---------------- Launch ------------------------------------------------------
extern "C" void kernel_launch(void* const* d_in, const int* in_sizes, int n_in,
                              void* d_out, int out_size, void* d_ws, size_t ws_size,
                              hipStream_t stream) {
    const float* zi = (const float*)d_in[0];
    const float* zj = (const float*)d_in[1];
    float* out = (float*)d_out;

    _Float16* Z = (_Float16*)d_ws;                                  // 4 MB
    float* rowsum = (float*)((char*)d_ws + (size_t)NN * DD * 2);    // 32 KB
    float* posPartial = rowsum + NN;                                // 4 KB

    nt_normalize<<<BB / 4, 256, 0, stream>>>(zi, zj, Z, posPartial, rowsum);
    nt_simexp<<<NBLK, 256, 0, stream>>>((const _Float16*)Z, rowsum);
    nt_finalize<<<1, 256, 0, stream>>>(rowsum, posPartial, out);
}